// Round 1
// baseline (672.079 us; speedup 1.0000x reference)
//
#include <hip/hip_runtime.h>
#include <hip/hip_bf16.h>

// NewellGRUModel: B=512, S=1024, F=16, H=64.  bf16 in/out (proven r2..r10).
//
// r12: wave-specialized producer/consumer. r11 post-mortem: per-step wall =
// 1373 cyc vs 384 cyc irreducible FMA issue; the gap is the per-step 4-wave
// barrier (vm/lgkm drain), the quad shfl-reduce, and 4x-redundant gate
// nonlinearities. New structure: one CONSUMER wave owns the whole batch
// recurrence -- all 192 rec-weight columns in VGPRs (__launch_bounds__(128,1)
// -> 512-reg budget), full 64-deep dot per lane, NO cross-lane reduce, NO
// per-step barrier (same-wave DS ops are in-order; h round-trips through a
// 64-float LDS buffer). A PRODUCER wave precomputes x_proj(+biases) per
// 16-step tile into LDS dbuf (it has ~4x slack) and the delta-channel sum.
// One barrier per 16 steps. 512 blocks x 128 thr = 1024 waves = 1/SIMD
// machine-wide.

#define KEEP(x) asm volatile("" : "+v"(x))

template<bool BF16>
struct IO {
    static __device__ __forceinline__ float ld(const void* p, int i) {
        if constexpr (BF16) {
            unsigned short u = ((const unsigned short*)p)[i];
            union { unsigned int ui; float f; } c; c.ui = (unsigned int)u << 16;
            return c.f;
        } else {
            return ((const float*)p)[i];
        }
    }
    static __device__ __forceinline__ void st(void* p, int i, float v) {
        if constexpr (BF16) ((__hip_bfloat16*)p)[i] = __float2bfloat16(v);
        else ((float*)p)[i] = v;
    }
    // 4 consecutive elements, i % 4 == 0 (8B-aligned bf16 / 16B-aligned fp32)
    static __device__ __forceinline__ float4 ld4(const void* p, int i) {
        if constexpr (BF16) {
            const ushort4 u = ((const ushort4*)p)[i >> 2];
            union { unsigned int ui; float f; } a, b, c, d;
            a.ui = (unsigned int)u.x << 16; b.ui = (unsigned int)u.y << 16;
            c.ui = (unsigned int)u.z << 16; d.ui = (unsigned int)u.w << 16;
            return make_float4(a.f, b.f, c.f, d.f);
        } else {
            return ((const float4*)p)[i >> 2];
        }
    }
};

// mode: 0 = buffers are bf16, 1 = buffers are fp32.
__global__ void detect_dtype_kernel(const void* rkbuf, int* flag) {
    const float* f = (const float*)rkbuf;
    int ok = 0;
    for (int i = 0; i < 64; ++i) {
        float a = fabsf(f[i]);
        ok += (a > 1e-5f && a < 2.0f) ? 1 : 0;
    }
    *flag = (ok >= 48) ? 1 : 0;
}

template<bool BF16>
__global__ __launch_bounds__(128, 1)
void gru_pc_kernel(const void* __restrict__ inp, const void* __restrict__ gk,
                   const void* __restrict__ rk,  const void* __restrict__ gb,
                   const void* __restrict__ w1,  const void* __restrict__ b1v,
                   const void* __restrict__ gam, const void* __restrict__ bet,
                   const void* __restrict__ muv, const void* __restrict__ vav,
                   const void* __restrict__ w2,  const void* __restrict__ bb2,
                   const void* __restrict__ Tp,  const int* __restrict__ mode,
                   void* __restrict__ out)
{
    const int want = BF16 ? 0 : 1;
    if (*mode != want) return;   // uniform branch, whole block exits

    const int b   = blockIdx.x;
    const int tid = threadIdx.x;   // 0..127
    const int w   = tid >> 6;      // wave 0 = consumer, wave 1 = producer
    const int l   = tid & 63;      // lane = output unit o

    // xp[buf][step][o][{z, r, xh, pad}] -- x_proj with biases folded in
    __shared__ __align__(16) float xp[2][16][64][4];   // 32 KB
    __shared__ __align__(16) float xs[16][16];         // raw x tile (producer)
    __shared__ __align__(16) float hs[64];             // h broadcast (consumer)
    __shared__ __align__(16) float sred[64];           // epilogue state
    __shared__ float dsh;                              // delta-channel sum

    using io = IO<BF16>;
    const int xbase = b * 16384;   // elements

    if (w == 1) {
        // ================= PRODUCER =================
        float kz[15], kr[15], kh[15];
#pragma unroll
        for (int c = 0; c < 15; ++c) {
            kz[c] = io::ld(gk, c*192 + l);
            kr[c] = io::ld(gk, c*192 + 64 + l);
            kh[c] = io::ld(gk, c*192 + 128 + l);
            KEEP(kz[c]); KEEP(kr[c]); KEEP(kh[c]);
        }
        // z/r biases fold b_i + b_r; xh carries only b_i (b_r.h stays with r*rh)
        const float bz  = io::ld(gb, l)      + io::ld(gb, 192 + l);
        const float br  = io::ld(gb, 64 + l) + io::ld(gb, 192 + 64 + l);
        const float bax = io::ld(gb, 128 + l);
        float dsum = 0.0f;

        auto produce = [&](int buf) {
#pragma unroll 1
            for (int s2 = 0; s2 < 16; ++s2) {
                const float4* xr = (const float4*)&xs[s2][0];   // uniform addr
                const float4 x0 = xr[0], x1 = xr[1], x2 = xr[2], x3 = xr[3];
                float az = bz, ar = br, ax = bax;
                az=fmaf(x0.x,kz[0],az);  ar=fmaf(x0.x,kr[0],ar);  ax=fmaf(x0.x,kh[0],ax);
                az=fmaf(x0.y,kz[1],az);  ar=fmaf(x0.y,kr[1],ar);  ax=fmaf(x0.y,kh[1],ax);
                az=fmaf(x0.z,kz[2],az);  ar=fmaf(x0.z,kr[2],ar);  ax=fmaf(x0.z,kh[2],ax);
                az=fmaf(x0.w,kz[3],az);  ar=fmaf(x0.w,kr[3],ar);  ax=fmaf(x0.w,kh[3],ax);
                az=fmaf(x1.x,kz[4],az);  ar=fmaf(x1.x,kr[4],ar);  ax=fmaf(x1.x,kh[4],ax);
                az=fmaf(x1.y,kz[5],az);  ar=fmaf(x1.y,kr[5],ar);  ax=fmaf(x1.y,kh[5],ax);
                az=fmaf(x1.z,kz[6],az);  ar=fmaf(x1.z,kr[6],ar);  ax=fmaf(x1.z,kh[6],ax);
                az=fmaf(x1.w,kz[7],az);  ar=fmaf(x1.w,kr[7],ar);  ax=fmaf(x1.w,kh[7],ax);
                az=fmaf(x2.x,kz[8],az);  ar=fmaf(x2.x,kr[8],ar);  ax=fmaf(x2.x,kh[8],ax);
                az=fmaf(x2.y,kz[9],az);  ar=fmaf(x2.y,kr[9],ar);  ax=fmaf(x2.y,kh[9],ax);
                az=fmaf(x2.z,kz[10],az); ar=fmaf(x2.z,kr[10],ar); ax=fmaf(x2.z,kh[10],ax);
                az=fmaf(x2.w,kz[11],az); ar=fmaf(x2.w,kr[11],ar); ax=fmaf(x2.w,kh[11],ax);
                az=fmaf(x3.x,kz[12],az); ar=fmaf(x3.x,kr[12],ar); ax=fmaf(x3.x,kh[12],ax);
                az=fmaf(x3.y,kz[13],az); ar=fmaf(x3.y,kr[13],ar); ax=fmaf(x3.y,kh[13],ax);
                az=fmaf(x3.z,kz[14],az); ar=fmaf(x3.z,kr[14],ar); ax=fmaf(x3.z,kh[14],ax);
                dsum += x3.w;            // ch15 = delta channel (lane-uniform)
                *(float4*)&xp[buf][s2][l][0] = make_float4(az, ar, ax, 0.0f);
            }
        };

        // tile 0
        {
            float4 v = io::ld4(inp, xbase + 4*l);
            ((float4*)xs)[l] = v;        // same-wave DS: in-order, no barrier
            produce(0);
        }
        __syncthreads();                 // B0: tile 0 ready

#pragma unroll 1
        for (int t = 0; t < 64; ++t) {
            if (t < 63) {
                float4 v = io::ld4(inp, xbase + (t + 1)*256 + 4*l);
                ((float4*)xs)[l] = v;
                produce((t + 1) & 1);    // stays 1 tile ahead of consumer
            } else if (l == 0) {
                dsh = dsum;              // all producer lanes hold the same sum
            }
            __syncthreads();             // B(t+1): tile t+1 ready / tile t free
        }
        return;
    }

    // ================= CONSUMER =================
    float wz[64], wr[64], wh[64];
#pragma unroll
    for (int i = 0; i < 64; ++i) {
        wz[i] = io::ld(rk, i*192 + l);
        wr[i] = io::ld(rk, i*192 + 64 + l);
        wh[i] = io::ld(rk, i*192 + 128 + l);
        KEEP(wz[i]); KEEP(wr[i]); KEEP(wh[i]);
    }
    const float bah = io::ld(gb, 192 + 128 + l);   // b_r[h]

    hs[l] = 0.0f;                        // h0 = 0 (consumer-private buffer)
    float h = 0.0f;
    __syncthreads();                     // B0

#pragma unroll 1
    for (int t = 0; t < 64; ++t) {
        const float (*xpt)[64][4] = xp[t & 1];
#pragma unroll 1
        for (int s2 = 0; s2 < 16; ++s2) {
            const float4 xpv = *(const float4*)&xpt[s2][l][0];   // z,r,xh
            const float4* hp = (const float4*)hs;                // uniform addr
            float az = xpv.x, ar = xpv.y, ax = xpv.z;
            float ah = bah;
            float az1 = 0.0f, ar1 = 0.0f, ah1 = 0.0f;
#pragma unroll
            for (int i = 0; i < 8; ++i) {
                const float4 p = hp[i];
                az = fmaf(p.x, wz[4*i+0], az); ar = fmaf(p.x, wr[4*i+0], ar); ah = fmaf(p.x, wh[4*i+0], ah);
                az = fmaf(p.y, wz[4*i+1], az); ar = fmaf(p.y, wr[4*i+1], ar); ah = fmaf(p.y, wh[4*i+1], ah);
                az = fmaf(p.z, wz[4*i+2], az); ar = fmaf(p.z, wr[4*i+2], ar); ah = fmaf(p.z, wh[4*i+2], ah);
                az = fmaf(p.w, wz[4*i+3], az); ar = fmaf(p.w, wr[4*i+3], ar); ah = fmaf(p.w, wh[4*i+3], ah);
            }
#pragma unroll
            for (int i = 8; i < 16; ++i) {
                const float4 p = hp[i];
                az1 = fmaf(p.x, wz[4*i+0], az1); ar1 = fmaf(p.x, wr[4*i+0], ar1); ah1 = fmaf(p.x, wh[4*i+0], ah1);
                az1 = fmaf(p.y, wz[4*i+1], az1); ar1 = fmaf(p.y, wr[4*i+1], ar1); ah1 = fmaf(p.y, wh[4*i+1], ah1);
                az1 = fmaf(p.z, wz[4*i+2], az1); ar1 = fmaf(p.z, wr[4*i+2], ar1); ah1 = fmaf(p.z, wh[4*i+2], ah1);
                az1 = fmaf(p.w, wz[4*i+3], az1); ar1 = fmaf(p.w, wr[4*i+3], ar1); ah1 = fmaf(p.w, wh[4*i+3], ah1);
            }
            az += az1; ar += ar1; ah += ah1;

            const float z   = __builtin_amdgcn_rcpf(1.0f + __expf(-az));
            const float r   = __builtin_amdgcn_rcpf(1.0f + __expf(-ar));
            const float pre = fmaf(r, ah, ax);
            const float e2  = __expf(2.0f * pre);
            const float th  = 1.0f - 2.0f * __builtin_amdgcn_rcpf(e2 + 1.0f);
            h = fmaf(z, h - th, th);     // z*h + (1-z)*tanh

            hs[l] = h;   // same-wave DS pipe is in-order: next read sees it
        }
        __syncthreads();                 // B(t+1): done with tile t
    }

    // ---- epilogue: delta effect + dense head (consumer wave only) ----
    const float T0 = io::ld(Tp, 0);
    const float state = fmaf(T0 * (1.0f / 1024.0f), dsh, h);
    sred[l] = state;                     // same-wave visibility, in-order DS

    const int j = l;                     // 0..63
    float acc = io::ld(b1v, j);
#pragma unroll
    for (int k = 0; k < 64; ++k)
        acc = fmaf(sred[k], io::ld(w1, k*64 + j), acc);
    acc = fmaxf(acc, 0.0f);                                  // ReLU
    const float inv = rsqrtf(io::ld(vav, j) + 0.001f);       // BN_EPS
    acc = fmaf((acc - io::ld(muv, j)) * inv, io::ld(gam, j), io::ld(bet, j));

    float v = acc * io::ld(w2, j);
#pragma unroll
    for (int off = 32; off > 0; off >>= 1)
        v += __shfl_down(v, off);
    if (j == 0) io::st(out, b, v + io::ld(bb2, 0));
}

extern "C" void kernel_launch(void* const* d_in, const int* in_sizes, int n_in,
                              void* d_out, int out_size, void* d_ws, size_t ws_size,
                              hipStream_t stream)
{
    const void* inp = d_in[0];   // (512,1024,16)
    const void* gk  = d_in[1];   // (15,192)
    const void* rk  = d_in[2];   // (64,192)
    const void* gb  = d_in[3];   // (2,192)
    const void* w1  = d_in[4];   // (64,64)
    const void* b1v = d_in[5];   // (64,)
    const void* gam = d_in[6];
    const void* bet = d_in[7];
    const void* muv = d_in[8];
    const void* vav = d_in[9];
    const void* w2  = d_in[10];  // (64,1)
    const void* bb2 = d_in[11];  // (1,)
    const void* Tp  = d_in[12];  // (1,)

    int* flag = (int*)d_ws;
    detect_dtype_kernel<<<dim3(1), dim3(1), 0, stream>>>(rk, flag);
    gru_pc_kernel<true ><<<dim3(512), dim3(128), 0, stream>>>(
        inp, gk, rk, gb, w1, b1v, gam, bet, muv, vav, w2, bb2, Tp, flag, d_out);
    gru_pc_kernel<false><<<dim3(512), dim3(128), 0, stream>>>(
        inp, gk, rk, gb, w1, b1v, gam, bet, muv, vav, w2, bb2, Tp, flag, d_out);
}

// Round 2
// 460.719 us; speedup vs baseline: 1.4588x; 1.4588x over previous
//
#include <hip/hip_runtime.h>
#include <hip/hip_bf16.h>

// NewellGRUModel: B=512, S=1024, F=16, H=64.  bf16 in/out (proven r2..r10).
//
// r13: r12 post-mortem -- VGPR_Count=132 with 192 live weight floats proves
// the compiler parked the recurrent weights in AGPRs (accvgpr_read per use,
// +~400 cyc/step) on a wave that runs ALONE on its SIMD (nothing hides the
// stalls). r11's VGPR=56 @ 60 weights shows the parking threshold is low;
// launch_bounds can't beat it. Fix: halve both the footprint AND the issue
// count with v_dot2_f32_f16 -- recurrent weights packed f16x2 (96 regs,
// bf16 -> f16 exact), h broadcast through LDS as packed f16 (8 uniform
// ds_read_b128, broadcast). 96 dot2/step (fp32 accumulate) instead of
// 192 fma + 192 accvgpr_read. Producer wave (x_proj + delta sum) unchanged;
// one barrier per 16 steps; zero barriers inside the step loop.

#define KEEP(x) asm volatile("" : "+v"(x))

typedef _Float16 f16x2 __attribute__((ext_vector_type(2)));
union H2U { unsigned int u; f16x2 h; };

#if defined(__has_builtin)
#  if __has_builtin(__builtin_amdgcn_fdot2)
#    define HAS_FDOT2 1
#  endif
#endif
#ifndef HAS_FDOT2
#  define HAS_FDOT2 0
#endif

// acc += h2[0]*w2[0] + h2[1]*w2[1]  (fp32 accumulate)
static __device__ __forceinline__ float dot2acc(unsigned int hraw, unsigned int wraw, float acc) {
    H2U a, b; a.u = hraw; b.u = wraw;
#if HAS_FDOT2
    return __builtin_amdgcn_fdot2(a.h, b.h, acc, false);
#else
    return fmaf((float)a.h.x, (float)b.h.x, fmaf((float)a.h.y, (float)b.h.y, acc));
#endif
}

template<bool BF16>
struct IO {
    static __device__ __forceinline__ float ld(const void* p, int i) {
        if constexpr (BF16) {
            unsigned short u = ((const unsigned short*)p)[i];
            union { unsigned int ui; float f; } c; c.ui = (unsigned int)u << 16;
            return c.f;
        } else {
            return ((const float*)p)[i];
        }
    }
    static __device__ __forceinline__ void st(void* p, int i, float v) {
        if constexpr (BF16) ((__hip_bfloat16*)p)[i] = __float2bfloat16(v);
        else ((float*)p)[i] = v;
    }
    // 4 consecutive elements, i % 4 == 0 (8B-aligned bf16 / 16B-aligned fp32)
    static __device__ __forceinline__ float4 ld4(const void* p, int i) {
        if constexpr (BF16) {
            const ushort4 u = ((const ushort4*)p)[i >> 2];
            union { unsigned int ui; float f; } a, b, c, d;
            a.ui = (unsigned int)u.x << 16; b.ui = (unsigned int)u.y << 16;
            c.ui = (unsigned int)u.z << 16; d.ui = (unsigned int)u.w << 16;
            return make_float4(a.f, b.f, c.f, d.f);
        } else {
            return ((const float4*)p)[i >> 2];
        }
    }
};

// mode: 0 = buffers are bf16, 1 = buffers are fp32.
__global__ void detect_dtype_kernel(const void* rkbuf, int* flag) {
    const float* f = (const float*)rkbuf;
    int ok = 0;
    for (int i = 0; i < 64; ++i) {
        float a = fabsf(f[i]);
        ok += (a > 1e-5f && a < 2.0f) ? 1 : 0;
    }
    *flag = (ok >= 48) ? 1 : 0;
}

template<bool BF16>
__global__ __launch_bounds__(128, 1)
void gru_pc_kernel(const void* __restrict__ inp, const void* __restrict__ gk,
                   const void* __restrict__ rk,  const void* __restrict__ gb,
                   const void* __restrict__ w1,  const void* __restrict__ b1v,
                   const void* __restrict__ gam, const void* __restrict__ bet,
                   const void* __restrict__ muv, const void* __restrict__ vav,
                   const void* __restrict__ w2,  const void* __restrict__ bb2,
                   const void* __restrict__ Tp,  const int* __restrict__ mode,
                   void* __restrict__ out)
{
    const int want = BF16 ? 0 : 1;
    if (*mode != want) return;   // uniform branch, whole block exits

    const int b   = blockIdx.x;
    const int tid = threadIdx.x;   // 0..127
    const int w   = tid >> 6;      // wave 0 = consumer, wave 1 = producer
    const int l   = tid & 63;      // lane = output unit o

    // xp[buf][step][o][{z, r, xh, pad}] -- x_proj with biases folded in
    __shared__ __align__(16) float xp[2][16][64][4];   // 32 KB
    __shared__ __align__(16) float xs[16][16];         // raw x tile (producer)
    __shared__ __align__(16) _Float16 hsf[64];         // h broadcast, packed f16
    __shared__ __align__(16) float sred[64];           // epilogue state
    __shared__ float dsh;                              // delta-channel sum

    using io = IO<BF16>;
    const int xbase = b * 16384;   // elements

    if (w == 1) {
        // ================= PRODUCER =================
        float kz[15], kr[15], kh[15];
#pragma unroll
        for (int c = 0; c < 15; ++c) {
            kz[c] = io::ld(gk, c*192 + l);
            kr[c] = io::ld(gk, c*192 + 64 + l);
            kh[c] = io::ld(gk, c*192 + 128 + l);
            KEEP(kz[c]); KEEP(kr[c]); KEEP(kh[c]);
        }
        // z/r biases fold b_i + b_r; xh carries only b_i (b_r.h stays with r*rh)
        const float bz  = io::ld(gb, l)      + io::ld(gb, 192 + l);
        const float br  = io::ld(gb, 64 + l) + io::ld(gb, 192 + 64 + l);
        const float bax = io::ld(gb, 128 + l);
        float dsum = 0.0f;

        auto produce = [&](int buf) {
#pragma unroll 1
            for (int s2 = 0; s2 < 16; ++s2) {
                const float4* xr = (const float4*)&xs[s2][0];   // uniform addr
                const float4 x0 = xr[0], x1 = xr[1], x2 = xr[2], x3 = xr[3];
                float az = bz, ar = br, ax = bax;
                az=fmaf(x0.x,kz[0],az);  ar=fmaf(x0.x,kr[0],ar);  ax=fmaf(x0.x,kh[0],ax);
                az=fmaf(x0.y,kz[1],az);  ar=fmaf(x0.y,kr[1],ar);  ax=fmaf(x0.y,kh[1],ax);
                az=fmaf(x0.z,kz[2],az);  ar=fmaf(x0.z,kr[2],ar);  ax=fmaf(x0.z,kh[2],ax);
                az=fmaf(x0.w,kz[3],az);  ar=fmaf(x0.w,kr[3],ar);  ax=fmaf(x0.w,kh[3],ax);
                az=fmaf(x1.x,kz[4],az);  ar=fmaf(x1.x,kr[4],ar);  ax=fmaf(x1.x,kh[4],ax);
                az=fmaf(x1.y,kz[5],az);  ar=fmaf(x1.y,kr[5],ar);  ax=fmaf(x1.y,kh[5],ax);
                az=fmaf(x1.z,kz[6],az);  ar=fmaf(x1.z,kr[6],ar);  ax=fmaf(x1.z,kh[6],ax);
                az=fmaf(x1.w,kz[7],az);  ar=fmaf(x1.w,kr[7],ar);  ax=fmaf(x1.w,kh[7],ax);
                az=fmaf(x2.x,kz[8],az);  ar=fmaf(x2.x,kr[8],ar);  ax=fmaf(x2.x,kh[8],ax);
                az=fmaf(x2.y,kz[9],az);  ar=fmaf(x2.y,kr[9],ar);  ax=fmaf(x2.y,kh[9],ax);
                az=fmaf(x2.z,kz[10],az); ar=fmaf(x2.z,kr[10],ar); ax=fmaf(x2.z,kh[10],ax);
                az=fmaf(x2.w,kz[11],az); ar=fmaf(x2.w,kr[11],ar); ax=fmaf(x2.w,kh[11],ax);
                az=fmaf(x3.x,kz[12],az); ar=fmaf(x3.x,kr[12],ar); ax=fmaf(x3.x,kh[12],ax);
                az=fmaf(x3.y,kz[13],az); ar=fmaf(x3.y,kr[13],ar); ax=fmaf(x3.y,kh[13],ax);
                az=fmaf(x3.z,kz[14],az); ar=fmaf(x3.z,kr[14],ar); ax=fmaf(x3.z,kh[14],ax);
                dsum += x3.w;            // ch15 = delta channel (lane-uniform)
                *(float4*)&xp[buf][s2][l][0] = make_float4(az, ar, ax, 0.0f);
            }
        };

        // tile 0
        {
            float4 v = io::ld4(inp, xbase + 4*l);
            ((float4*)xs)[l] = v;        // same-wave DS: in-order, no barrier
            produce(0);
        }
        __syncthreads();                 // B0: tile 0 ready

#pragma unroll 1
        for (int t = 0; t < 64; ++t) {
            if (t < 63) {
                float4 v = io::ld4(inp, xbase + (t + 1)*256 + 4*l);
                ((float4*)xs)[l] = v;
                produce((t + 1) & 1);    // stays 1 tile ahead of consumer
            } else if (l == 0) {
                dsh = dsum;              // all producer lanes hold the same sum
            }
            __syncthreads();             // B(t+1): tile t+1 ready / tile t free
        }
        return;
    }

    // ================= CONSUMER =================
    // Recurrent weights packed f16x2: pair p covers k = 2p, 2p+1.
    // 96 VGPRs total (bf16 -> f16 is exact for this value range).
    unsigned int wzp[32], wrp[32], whp[32];
#pragma unroll
    for (int p = 0; p < 32; ++p) {
        H2U z, r, hh;
        z.h  = f16x2{(_Float16)io::ld(rk, (2*p)*192 + l),
                     (_Float16)io::ld(rk, (2*p+1)*192 + l)};
        r.h  = f16x2{(_Float16)io::ld(rk, (2*p)*192 + 64 + l),
                     (_Float16)io::ld(rk, (2*p+1)*192 + 64 + l)};
        hh.h = f16x2{(_Float16)io::ld(rk, (2*p)*192 + 128 + l),
                     (_Float16)io::ld(rk, (2*p+1)*192 + 128 + l)};
        wzp[p] = z.u; wrp[p] = r.u; whp[p] = hh.u;
        KEEP(wzp[p]); KEEP(wrp[p]); KEEP(whp[p]);
    }
    const float bah = io::ld(gb, 192 + 128 + l);   // b_r[h]

    hsf[l] = (_Float16)0.0f;             // h0 = 0 (consumer-private buffer)
    float h = 0.0f;
    __syncthreads();                     // B0

#pragma unroll 1
    for (int t = 0; t < 64; ++t) {
        const float (*xpt)[64][4] = xp[t & 1];
#pragma unroll 1
        for (int s2 = 0; s2 < 16; ++s2) {
            const float4 xpv = *(const float4*)&xpt[s2][l][0];   // z,r,xh
            const uint4* hp = (const uint4*)hsf;   // 64 halves = 8 uint4, uniform
            float az = xpv.x, ar = xpv.y;
            const float ax = xpv.z;
            float ah = bah;
            float az1 = 0.0f, ar1 = 0.0f, ah1 = 0.0f;
            // uint4 i: dwords = h-pairs 4i..4i+3 (halves 8i..8i+7)
#pragma unroll
            for (int i = 0; i < 4; ++i) {
                const uint4 d = hp[i];
                az = dot2acc(d.x, wzp[4*i+0], az); ar = dot2acc(d.x, wrp[4*i+0], ar); ah = dot2acc(d.x, whp[4*i+0], ah);
                az = dot2acc(d.y, wzp[4*i+1], az); ar = dot2acc(d.y, wrp[4*i+1], ar); ah = dot2acc(d.y, whp[4*i+1], ah);
                az = dot2acc(d.z, wzp[4*i+2], az); ar = dot2acc(d.z, wrp[4*i+2], ar); ah = dot2acc(d.z, whp[4*i+2], ah);
                az = dot2acc(d.w, wzp[4*i+3], az); ar = dot2acc(d.w, wrp[4*i+3], ar); ah = dot2acc(d.w, whp[4*i+3], ah);
            }
#pragma unroll
            for (int i = 4; i < 8; ++i) {
                const uint4 d = hp[i];
                az1 = dot2acc(d.x, wzp[4*i+0], az1); ar1 = dot2acc(d.x, wrp[4*i+0], ar1); ah1 = dot2acc(d.x, whp[4*i+0], ah1);
                az1 = dot2acc(d.y, wzp[4*i+1], az1); ar1 = dot2acc(d.y, wrp[4*i+1], ar1); ah1 = dot2acc(d.y, whp[4*i+1], ah1);
                az1 = dot2acc(d.z, wzp[4*i+2], az1); ar1 = dot2acc(d.z, wrp[4*i+2], ar1); ah1 = dot2acc(d.z, whp[4*i+2], ah1);
                az1 = dot2acc(d.w, wzp[4*i+3], az1); ar1 = dot2acc(d.w, wrp[4*i+3], ar1); ah1 = dot2acc(d.w, whp[4*i+3], ah1);
            }
            az += az1; ar += ar1; ah += ah1;

            const float z   = __builtin_amdgcn_rcpf(1.0f + __expf(-az));
            const float r   = __builtin_amdgcn_rcpf(1.0f + __expf(-ar));
            const float pre = fmaf(r, ah, ax);
            const float e2  = __expf(2.0f * pre);
            const float th  = 1.0f - 2.0f * __builtin_amdgcn_rcpf(e2 + 1.0f);
            h = fmaf(z, h - th, th);     // z*h + (1-z)*tanh

            hsf[l] = (_Float16)h;  // same-wave DS pipe is in-order: next read sees it
        }
        __syncthreads();                 // B(t+1): done with tile t
    }

    // ---- epilogue: delta effect + dense head (consumer wave only) ----
    const float T0 = io::ld(Tp, 0);
    const float state = fmaf(T0 * (1.0f / 1024.0f), dsh, h);   // fp32 h
    sred[l] = state;                     // same-wave visibility, in-order DS

    const int j = l;                     // 0..63
    float acc = io::ld(b1v, j);
#pragma unroll
    for (int k = 0; k < 64; ++k)
        acc = fmaf(sred[k], io::ld(w1, k*64 + j), acc);
    acc = fmaxf(acc, 0.0f);                                  // ReLU
    const float inv = rsqrtf(io::ld(vav, j) + 0.001f);       // BN_EPS
    acc = fmaf((acc - io::ld(muv, j)) * inv, io::ld(gam, j), io::ld(bet, j));

    float v = acc * io::ld(w2, j);
#pragma unroll
    for (int off = 32; off > 0; off >>= 1)
        v += __shfl_down(v, off);
    if (j == 0) io::st(out, b, v + io::ld(bb2, 0));
}

extern "C" void kernel_launch(void* const* d_in, const int* in_sizes, int n_in,
                              void* d_out, int out_size, void* d_ws, size_t ws_size,
                              hipStream_t stream)
{
    const void* inp = d_in[0];   // (512,1024,16)
    const void* gk  = d_in[1];   // (15,192)
    const void* rk  = d_in[2];   // (64,192)
    const void* gb  = d_in[3];   // (2,192)
    const void* w1  = d_in[4];   // (64,64)
    const void* b1v = d_in[5];   // (64,)
    const void* gam = d_in[6];
    const void* bet = d_in[7];
    const void* muv = d_in[8];
    const void* vav = d_in[9];
    const void* w2  = d_in[10];  // (64,1)
    const void* bb2 = d_in[11];  // (1,)
    const void* Tp  = d_in[12];  // (1,)

    int* flag = (int*)d_ws;
    detect_dtype_kernel<<<dim3(1), dim3(1), 0, stream>>>(rk, flag);
    gru_pc_kernel<true ><<<dim3(512), dim3(128), 0, stream>>>(
        inp, gk, rk, gb, w1, b1v, gam, bet, muv, vav, w2, bb2, Tp, flag, d_out);
    gru_pc_kernel<false><<<dim3(512), dim3(128), 0, stream>>>(
        inp, gk, rk, gb, w1, b1v, gam, bet, muv, vav, w2, bb2, Tp, flag, d_out);
}